// Round 1
// baseline (881.632 us; speedup 1.0000x reference)
//
#include <hip/hip_runtime.h>
#include <math.h>

// STN3d: conv(3->64)->BN->ReLU, conv(64->128)->BN->ReLU, conv(128->1024)->BN->ReLU,
// maxpool over N, FC 1024->512->256->128 each +BN+ReLU, FC->3 angles, Euler->R.
// BN is training-mode (batch stats). B=32, C=3, N=4096.
//
// Workspace layout (floats): h2_pre [32][128][4096] = 16,777,216 floats (64 MiB),
// then ~800 KB of accumulators. Requires ws_size >= ~68 MB.

#define EPS 1e-5f
#define PI_F 3.1415927410125732f

__device__ __forceinline__ unsigned encf(float f) {
  unsigned u = __float_as_uint(f);
  return (u & 0x80000000u) ? ~u : (u | 0x80000000u);
}
__device__ __forceinline__ float decf(unsigned u) {
  return __uint_as_float((u & 0x80000000u) ? (u ^ 0x80000000u) : ~u);
}

// ---------------- layer1 stats (h1_pre computed on the fly, never stored) ------------
__global__ __launch_bounds__(64) void k1_stats1(const float* __restrict__ x,
    const float* __restrict__ w1, const float* __restrict__ b1,
    float* __restrict__ sum1, float* __restrict__ sq1) {
  int blk = blockIdx.x;            // 512 blocks: b = blk>>4, 16 chunks of 256 points
  int b = blk >> 4, chunk = blk & 15;
  int o = threadIdx.x;             // channel 0..63
  float wa = w1[o*3+0], wb = w1[o*3+1], wc = w1[o*3+2], bias = b1[o];
  const float* xb = x + ((size_t)b*3)*4096 + chunk*256;
  float s = 0.f, s2 = 0.f;
  #pragma unroll 4
  for (int n = 0; n < 256; ++n) {
    float v = fmaf(wa, xb[n], fmaf(wb, xb[4096+n], fmaf(wc, xb[8192+n], bias)));
    s += v; s2 = fmaf(v, v, s2);
  }
  atomicAdd(&sum1[o], s);
  atomicAdd(&sq1[o], s2);
}

// ---------------- finalize BN stats -> scale/shift --------------------------------
__global__ void k_finstats(const float* __restrict__ sum, const float* __restrict__ sq,
    const float* __restrict__ g, const float* __restrict__ be,
    float* __restrict__ scale, float* __restrict__ shift, int F, int nPart) {
  int o = blockIdx.x*blockDim.x + threadIdx.x;
  if (o >= F) return;
  float s = 0.f, s2 = 0.f;
  for (int p = 0; p < nPart; ++p) { s += sum[p*F+o]; s2 += sq[p*F+o]; }
  const float inv = 1.f/131072.f;
  float m = s*inv, v = s2*inv - m*m;
  float sc = g[o]*rsqrtf(v + EPS);
  scale[o] = sc;
  shift[o] = be[o] - sc*m;
}

// ---------------- layer2: recompute h1 tile, GEMM 64->128, write h2_pre, stats2 ----
__global__ __launch_bounds__(256) void k3_layer2(const float* __restrict__ x,
    const float* __restrict__ w1, const float* __restrict__ b1,
    const float* __restrict__ scale1, const float* __restrict__ shift1,
    const float* __restrict__ w2, const float* __restrict__ b2,
    float* __restrict__ h2, float* __restrict__ sum2, float* __restrict__ sq2) {
  __shared__ float xs[3][64];
  __shared__ float w1s[64][3];
  __shared__ float b1s[64], sc1s[64], sh1s[64];
  __shared__ float h1s[64][64];     // [k][n]
  __shared__ float w2s[128][64];    // [o][k], column-XOR-swizzled
  int t = threadIdx.x;
  int tile = blockIdx.x;            // 0..2047  (64-point tiles over B*N)
  int b = tile >> 6;
  int n0 = (tile & 63) << 6;
  if (t < 192) { int c = t >> 6, n = t & 63; xs[c][n] = x[((size_t)b*3 + c)*4096 + n0 + n]; }
  if (t < 64) {
    b1s[t] = b1[t]; sc1s[t] = scale1[t]; sh1s[t] = shift1[t];
    w1s[t][0] = w1[t*3+0]; w1s[t][1] = w1[t*3+1]; w1s[t][2] = w1[t*3+2];
  }
  for (int v = t; v < 2048; v += 256) {         // stage w2 (128x64)
    int row = v >> 4, c4 = (v & 15) << 2;
    int sw = ((row >> 3) & 3) << 2;
    *(float4*)(&w2s[row][c4 ^ sw]) = *(const float4*)(w2 + row*64 + c4);
  }
  __syncthreads();
  for (int idx = t; idx < 4096; idx += 256) {   // h1 tile = relu(bn1(w1@x + b1))
    int o = idx >> 6, n = idx & 63;
    float pre = fmaf(w1s[o][0], xs[0][n], fmaf(w1s[o][1], xs[1][n], fmaf(w1s[o][2], xs[2][n], b1s[o])));
    h1s[o][n] = fmaxf(fmaf(sc1s[o], pre, sh1s[o]), 0.f);
  }
  __syncthreads();
  int to = t >> 4, tn = t & 15;
  int ob = to << 3, nb = tn << 2;               // 8 o-rows, 4 n-cols per thread
  int swz = (to & 3) << 2;
  float acc[8][4];
  #pragma unroll
  for (int i = 0; i < 8; ++i) { float bb = b2[ob+i]; acc[i][0]=bb; acc[i][1]=bb; acc[i][2]=bb; acc[i][3]=bb; }
  #pragma unroll 2
  for (int k0 = 0; k0 < 64; k0 += 4) {
    float4 bv[4];
    #pragma unroll
    for (int kk = 0; kk < 4; ++kk) bv[kk] = *(const float4*)(&h1s[k0+kk][nb]);
    #pragma unroll
    for (int i = 0; i < 8; ++i) {
      float4 av = *(const float4*)(&w2s[ob+i][k0 ^ swz]);
      const float* ap = (const float*)&av;
      #pragma unroll
      for (int kk = 0; kk < 4; ++kk) {
        const float* bp = (const float*)&bv[kk];
        #pragma unroll
        for (int j = 0; j < 4; ++j) acc[i][j] = fmaf(ap[kk], bp[j], acc[i][j]);
      }
    }
  }
  size_t obase = ((size_t)b*128)*4096 + n0 + nb;
  #pragma unroll
  for (int i = 0; i < 8; ++i) {
    int o = ob + i;
    *(float4*)(h2 + obase + (size_t)o*4096) = make_float4(acc[i][0], acc[i][1], acc[i][2], acc[i][3]);
    float s  = acc[i][0]+acc[i][1]+acc[i][2]+acc[i][3];
    float s2 = fmaf(acc[i][0],acc[i][0], fmaf(acc[i][1],acc[i][1], fmaf(acc[i][2],acc[i][2], acc[i][3]*acc[i][3])));
    #pragma unroll
    for (int d = 1; d < 16; d <<= 1) { s += __shfl_xor(s, d); s2 += __shfl_xor(s2, d); }
    if (tn == 0) { atomicAdd(&sum2[b*128+o], s); atomicAdd(&sq2[b*128+o], s2); }
  }
}

// ---------------- layer3: GEMM 128->1024 fused with stats3 + per-(b,o) max/min ----
__global__ __launch_bounds__(256) void k5_layer3(const float* __restrict__ h2,
    const float* __restrict__ scale2, const float* __restrict__ shift2,
    const float* __restrict__ w3, const float* __restrict__ b3,
    float* __restrict__ sum3, float* __restrict__ sq3,
    unsigned* __restrict__ maxe, unsigned* __restrict__ mine) {
  __shared__ float h2s[128][64];    // [k][n], bn2+relu applied
  __shared__ float w3s[64][128];    // [o][k], column-XOR-swizzled  (total LDS = 64 KiB)
  int t = threadIdx.x;
  int o0 = blockIdx.x << 6;         // 16 o-tiles
  int ntile = blockIdx.y;           // 2048 n-tiles
  int b = ntile >> 6;
  int n0 = (ntile & 63) << 6;
  const float* h2b = h2 + ((size_t)b*128)*4096 + n0;
  for (int v = t; v < 2048; v += 256) {         // stage h2 tile with bn2+relu
    int k = v >> 4, c4 = (v & 15) << 2;
    float4 f = *(const float4*)(h2b + (size_t)k*4096 + c4);
    float sc = scale2[k], sh = shift2[k];
    f.x = fmaxf(fmaf(sc, f.x, sh), 0.f);
    f.y = fmaxf(fmaf(sc, f.y, sh), 0.f);
    f.z = fmaxf(fmaf(sc, f.z, sh), 0.f);
    f.w = fmaxf(fmaf(sc, f.w, sh), 0.f);
    *(float4*)(&h2s[k][c4]) = f;
  }
  for (int v = t; v < 2048; v += 256) {         // stage w3 tile (64x128)
    int row = v >> 5, c4 = (v & 31) << 2;
    int sw = ((row >> 2) & 3) << 2;
    *(float4*)(&w3s[row][c4 ^ sw]) = *(const float4*)(w3 + ((size_t)(o0 + row))*128 + c4);
  }
  __syncthreads();
  int to = t >> 4, tn = t & 15;
  int ob = to << 2, nb = tn << 2;               // 4 o-rows, 4 n-cols per thread
  int swz = (to & 3) << 2;
  float acc[4][4];
  #pragma unroll
  for (int i = 0; i < 4; ++i) { float bb = b3[o0+ob+i]; acc[i][0]=bb; acc[i][1]=bb; acc[i][2]=bb; acc[i][3]=bb; }
  #pragma unroll 2
  for (int k0 = 0; k0 < 128; k0 += 4) {
    float4 bv[4];
    #pragma unroll
    for (int kk = 0; kk < 4; ++kk) bv[kk] = *(const float4*)(&h2s[k0+kk][nb]);
    #pragma unroll
    for (int i = 0; i < 4; ++i) {
      float4 av = *(const float4*)(&w3s[ob+i][k0 ^ swz]);
      const float* ap = (const float*)&av;
      #pragma unroll
      for (int kk = 0; kk < 4; ++kk) {
        const float* bp = (const float*)&bv[kk];
        #pragma unroll
        for (int j = 0; j < 4; ++j) acc[i][j] = fmaf(ap[kk], bp[j], acc[i][j]);
      }
    }
  }
  #pragma unroll
  for (int i = 0; i < 4; ++i) {
    float s  = acc[i][0]+acc[i][1]+acc[i][2]+acc[i][3];
    float s2 = fmaf(acc[i][0],acc[i][0], fmaf(acc[i][1],acc[i][1], fmaf(acc[i][2],acc[i][2], acc[i][3]*acc[i][3])));
    float mx = fmaxf(fmaxf(acc[i][0],acc[i][1]), fmaxf(acc[i][2],acc[i][3]));
    float mn = fminf(fminf(acc[i][0],acc[i][1]), fminf(acc[i][2],acc[i][3]));
    #pragma unroll
    for (int d = 1; d < 16; d <<= 1) {
      s += __shfl_xor(s, d); s2 += __shfl_xor(s2, d);
      mx = fmaxf(mx, __shfl_xor(mx, d));
      mn = fminf(mn, __shfl_xor(mn, d));
    }
    if (tn == 0) {
      int go = b*1024 + o0 + ob + i;
      atomicAdd(&sum3[go], s); atomicAdd(&sq3[go], s2);
      atomicMax(&maxe[go], encf(mx)); atomicMin(&mine[go], encf(mn));
    }
  }
}

// ---------------- finalize stats3 + pooled = relu(bn3(max/min)) -------------------
__global__ void k_fin3_pool(const float* __restrict__ sum3, const float* __restrict__ sq3,
    const unsigned* __restrict__ maxe, const unsigned* __restrict__ mine,
    const float* __restrict__ g, const float* __restrict__ be, float* __restrict__ pool) {
  int o = blockIdx.x*256 + threadIdx.x;   // 4 blocks x 256 = 1024
  float s = 0.f, s2 = 0.f;
  for (int b = 0; b < 32; ++b) { s += sum3[b*1024+o]; s2 += sq3[b*1024+o]; }
  const float inv = 1.f/131072.f;
  float m = s*inv, v = s2*inv - m*m;
  float sc = g[o]*rsqrtf(v + EPS);
  float sh = be[o] - sc*m;
  bool pos = (sc >= 0.f);   // monotone: max of bn = bn of max (or min if scale<0)
  for (int b = 0; b < 32; ++b) {
    unsigned e = pos ? maxe[b*1024+o] : mine[b*1024+o];
    pool[b*1024+o] = fmaxf(fmaf(sc, decf(e), sh), 0.f);
  }
}

// ---------------- fused FC + batch-BN + ReLU (one feature per block) --------------
__global__ __launch_bounds__(256) void k_fc_bn_relu(const float* __restrict__ in,
    const float* __restrict__ w, const float* __restrict__ fb,
    const float* __restrict__ g, const float* __restrict__ be,
    float* __restrict__ out, int K, int F) {
  __shared__ float wrow[1024];
  __shared__ float preb[32];
  int o = blockIdx.x, t = threadIdx.x;
  for (int k = t; k < K; k += 256) wrow[k] = w[(size_t)o*K + k];
  __syncthreads();
  int b = t >> 3, j = t & 7;                 // 32 batch x 8 lanes
  int per = K >> 3;
  const float* inb = in + (size_t)b*K + j*per;
  const float* wp  = wrow + j*per;
  float p = 0.f;
  for (int k = 0; k < per; ++k) p = fmaf(inb[k], wp[k], p);
  p += __shfl_xor(p, 1); p += __shfl_xor(p, 2); p += __shfl_xor(p, 4);
  if (j == 0) preb[b] = p + fb[o];
  __syncthreads();
  if (t < 32) {
    float v = preb[t];
    float s = v;
    #pragma unroll
    for (int d = 1; d < 32; d <<= 1) s += __shfl_xor(s, d);
    float m = s * 0.03125f;
    float dv = v - m;
    float q = dv*dv;
    #pragma unroll
    for (int d = 1; d < 32; d <<= 1) q += __shfl_xor(q, d);
    float var = q * 0.03125f;
    float sc = g[o]*rsqrtf(var + EPS);
    out[(size_t)t*F + o] = fmaxf(fmaf(sc, dv, be[o]), 0.f);
  }
}

// ---------------- angles + Euler->rotation ---------------------------------------
__global__ __launch_bounds__(128) void k_final(const float* __restrict__ h6,
    const float* __restrict__ fw4, const float* __restrict__ fb4, float* __restrict__ out) {
  __shared__ float angs[32][3];
  int t = threadIdx.x;
  if (t < 96) {
    int b = t / 3, j = t % 3;
    float p = 0.f;
    #pragma unroll 4
    for (int k = 0; k < 128; ++k) p = fmaf(h6[b*128+k], fw4[j*128+k], p);
    angs[b][j] = (p + fb4[j]) * PI_F;
  }
  __syncthreads();
  if (t < 32) {
    float a = angs[t][0], bb = angs[t][1], c = angs[t][2];
    float sa, ca; sincosf(a,  &sa, &ca);
    float sb, cb; sincosf(bb, &sb, &cb);
    float sc, cc; sincosf(c,  &sc, &cc);
    float* o9 = out + t*9;   // R = Rz @ Ry @ Rx
    o9[0] = cc*cb;
    o9[1] = fmaf(cc*sb, sa, -sc*ca);
    o9[2] = fmaf(cc*sb, ca,  sc*sa);
    o9[3] = sc*cb;
    o9[4] = fmaf(sc*sb, sa,  cc*ca);
    o9[5] = fmaf(sc*sb, ca, -cc*sa);
    o9[6] = -sb;
    o9[7] = cb*sa;
    o9[8] = cb*ca;
  }
}

extern "C" void kernel_launch(void* const* d_in, const int* in_sizes, int n_in,
                              void* d_out, int out_size, void* d_ws, size_t ws_size,
                              hipStream_t stream) {
  (void)in_sizes; (void)n_in; (void)out_size; (void)ws_size;
  const float* x   = (const float*)d_in[0];
  const float* w1  = (const float*)d_in[1];
  const float* b1  = (const float*)d_in[2];
  const float* g1  = (const float*)d_in[3];
  const float* be1 = (const float*)d_in[4];
  const float* w2  = (const float*)d_in[5];
  const float* b2  = (const float*)d_in[6];
  const float* g2  = (const float*)d_in[7];
  const float* be2 = (const float*)d_in[8];
  const float* w3  = (const float*)d_in[9];
  const float* b3  = (const float*)d_in[10];
  const float* g3  = (const float*)d_in[11];
  const float* be3 = (const float*)d_in[12];
  const float* fw1 = (const float*)d_in[13];
  const float* fb1 = (const float*)d_in[14];
  const float* g4  = (const float*)d_in[15];
  const float* be4 = (const float*)d_in[16];
  const float* fw2 = (const float*)d_in[17];
  const float* fb2 = (const float*)d_in[18];
  const float* g5p = (const float*)d_in[19];
  const float* be5 = (const float*)d_in[20];
  const float* fw3 = (const float*)d_in[21];
  const float* fb3 = (const float*)d_in[22];
  const float* g6  = (const float*)d_in[23];
  const float* be6 = (const float*)d_in[24];
  const float* fw4 = (const float*)d_in[25];
  const float* fb4 = (const float*)d_in[26];

  float* ws   = (float*)d_ws;
  float* h2v  = ws;                        // 16,777,216 floats (64 MiB)
  float* acc0 = ws + 16777216;
  float* sum1 = acc0 +      0;             // 64
  float* sq1  = acc0 +     64;             // 64
  float* sum2 = acc0 +    128;             // 32*128
  float* sq2  = acc0 +   4224;             // 32*128
  float* sum3 = acc0 +   8320;             // 32*1024
  float* sq3  = acc0 +  41088;             // 32*1024
  unsigned* maxe = (unsigned*)(acc0 +  73856);  // 32*1024
  unsigned* mine = (unsigned*)(acc0 + 106624);  // 32*1024
  float* scale1 = acc0 + 139392;
  float* shift1 = acc0 + 139456;
  float* scale2 = acc0 + 139520;
  float* shift2 = acc0 + 139648;
  float* pool   = acc0 + 139776;           // 32*1024
  float* h4v    = acc0 + 172544;           // 32*512
  float* h5v    = acc0 + 188928;           // 32*256
  float* h6v    = acc0 + 197120;           // 32*128

  // zero sums/sumsq/maxenc ; minenc -> 0xFFFFFFFF (= +inf in monotone encoding)
  hipMemsetAsync(acc0, 0, 106624ull*4, stream);
  hipMemsetAsync(mine, 0xFF, 32768ull*4, stream);

  k1_stats1<<<512, 64, 0, stream>>>(x, w1, b1, sum1, sq1);
  k_finstats<<<1, 64, 0, stream>>>(sum1, sq1, g1, be1, scale1, shift1, 64, 1);
  k3_layer2<<<2048, 256, 0, stream>>>(x, w1, b1, scale1, shift1, w2, b2, h2v, sum2, sq2);
  k_finstats<<<1, 128, 0, stream>>>(sum2, sq2, g2, be2, scale2, shift2, 128, 32);
  k5_layer3<<<dim3(16, 2048), 256, 0, stream>>>(h2v, scale2, shift2, w3, b3, sum3, sq3, maxe, mine);
  k_fin3_pool<<<4, 256, 0, stream>>>(sum3, sq3, maxe, mine, g3, be3, pool);
  k_fc_bn_relu<<<512, 256, 0, stream>>>(pool, fw1, fb1, g4, be4, h4v, 1024, 512);
  k_fc_bn_relu<<<256, 256, 0, stream>>>(h4v, fw2, fb2, g5p, be5, h5v, 512, 256);
  k_fc_bn_relu<<<128, 256, 0, stream>>>(h5v, fw3, fb3, g6, be6, h6v, 256, 128);
  k_final<<<1, 128, 0, stream>>>(h6v, fw4, fb4, (float*)d_out);
}

// Round 3
// 260.460 us; speedup vs baseline: 3.3849x; 3.3849x over previous
//
#include <hip/hip_runtime.h>
#include <math.h>

// STN3d, B=32, C=3, N=4096. Training-mode BN (batch stats).
// Pipeline:
//  k1_stats1: BN1 stats (h1 recomputed on the fly)
//  k2_stats2: recompute h1 tile -> GEMM 64->128 (f32) -> BN2 stats only (no store)
//  k3_split:  same GEMM -> bn2+relu -> bf16 hi/lo split -> h2t planes [b][n][128]
//  k5_layer3: bf16x3 MFMA GEMM 128->1024 (A_hi*B_hi + A_hi*B_lo + A_lo*B_hi),
//             fused f32 BN3 stats + per-(b,o) max/min (no atomics)
//  k_fin3_pool: finalize BN3 (+bias fold) + pooled = relu(bn3(extreme))
//  3x k_fc_bn_relu, k_final (Euler->R)
// Workspace: h2t_hi 32MB + h2t_lo 32MB + ~0.8MB accumulators (<= 68MB, proven).

#define EPS 1e-5f
#define PI_F 3.1415927410125732f

typedef unsigned int u32;
typedef unsigned short u16;
typedef __bf16 bf16x8 __attribute__((ext_vector_type(8)));
typedef float f32x4 __attribute__((ext_vector_type(4)));

__device__ __forceinline__ u16 f2bf(float f) {
  u32 u = __float_as_uint(f);
  return (u16)((u + 0x7FFFu + ((u >> 16) & 1u)) >> 16);
}
__device__ __forceinline__ float bf2f(u16 h) { return __uint_as_float(((u32)h) << 16); }

// ---------------- layer1 stats ----------------------------------------------------
__global__ __launch_bounds__(64) void k1_stats1(const float* __restrict__ x,
    const float* __restrict__ w1, const float* __restrict__ b1,
    float* __restrict__ sum1, float* __restrict__ sq1) {
  int blk = blockIdx.x;
  int b = blk >> 4, chunk = blk & 15;
  int o = threadIdx.x;
  float wa = w1[o*3+0], wb = w1[o*3+1], wc = w1[o*3+2], bias = b1[o];
  const float* xb = x + ((size_t)b*3)*4096 + chunk*256;
  float s = 0.f, s2 = 0.f;
  #pragma unroll 4
  for (int n = 0; n < 256; ++n) {
    float v = fmaf(wa, xb[n], fmaf(wb, xb[4096+n], fmaf(wc, xb[8192+n], bias)));
    s += v; s2 = fmaf(v, v, s2);
  }
  atomicAdd(&sum1[o], s);
  atomicAdd(&sq1[o], s2);
}

// ---------------- finalize BN stats -> scale/shift --------------------------------
__global__ void k_finstats(const float* __restrict__ sum, const float* __restrict__ sq,
    const float* __restrict__ g, const float* __restrict__ be,
    float* __restrict__ scale, float* __restrict__ shift, int F, int nPart) {
  int o = blockIdx.x*blockDim.x + threadIdx.x;
  if (o >= F) return;
  float s = 0.f, s2 = 0.f;
  for (int p = 0; p < nPart; ++p) { s += sum[p*F+o]; s2 += sq[p*F+o]; }
  const float inv = 1.f/131072.f;
  float m = s*inv, v = s2*inv - m*m;
  float sc = g[o]*rsqrtf(v + EPS);
  scale[o] = sc;
  shift[o] = be[o] - sc*m;
}

// ---------------- k2: layer2 GEMM (f32) -> BN2 stats only -------------------------
__global__ __launch_bounds__(256) void k2_stats2(const float* __restrict__ x,
    const float* __restrict__ w1, const float* __restrict__ b1,
    const float* __restrict__ scale1, const float* __restrict__ shift1,
    const float* __restrict__ w2, const float* __restrict__ b2,
    float* __restrict__ sum2, float* __restrict__ sq2) {
  __shared__ float xs[3][64];
  __shared__ float w1s[64][3];
  __shared__ float b1s[64], sc1s[64], sh1s[64];
  __shared__ float h1s[64][64];
  __shared__ float w2s[128][64];
  int t = threadIdx.x;
  int tile = blockIdx.x;
  int b = tile >> 6;
  int n0 = (tile & 63) << 6;
  if (t < 192) { int c = t >> 6, n = t & 63; xs[c][n] = x[((size_t)b*3 + c)*4096 + n0 + n]; }
  if (t < 64) {
    b1s[t] = b1[t]; sc1s[t] = scale1[t]; sh1s[t] = shift1[t];
    w1s[t][0] = w1[t*3+0]; w1s[t][1] = w1[t*3+1]; w1s[t][2] = w1[t*3+2];
  }
  for (int v = t; v < 2048; v += 256) {
    int row = v >> 4, c4 = (v & 15) << 2;
    int sw = ((row >> 3) & 3) << 2;
    *(float4*)(&w2s[row][c4 ^ sw]) = *(const float4*)(w2 + row*64 + c4);
  }
  __syncthreads();
  for (int idx = t; idx < 4096; idx += 256) {
    int o = idx >> 6, n = idx & 63;
    float pre = fmaf(w1s[o][0], xs[0][n], fmaf(w1s[o][1], xs[1][n], fmaf(w1s[o][2], xs[2][n], b1s[o])));
    h1s[o][n] = fmaxf(fmaf(sc1s[o], pre, sh1s[o]), 0.f);
  }
  __syncthreads();
  int to = t >> 4, tn = t & 15;
  int ob = to << 3, nb = tn << 2;
  int swz = (to & 3) << 2;
  float acc[8][4];
  #pragma unroll
  for (int i = 0; i < 8; ++i) { float bb = b2[ob+i]; acc[i][0]=bb; acc[i][1]=bb; acc[i][2]=bb; acc[i][3]=bb; }
  #pragma unroll 2
  for (int k0 = 0; k0 < 64; k0 += 4) {
    float4 bv[4];
    #pragma unroll
    for (int kk = 0; kk < 4; ++kk) bv[kk] = *(const float4*)(&h1s[k0+kk][nb]);
    #pragma unroll
    for (int i = 0; i < 8; ++i) {
      float4 av = *(const float4*)(&w2s[ob+i][k0 ^ swz]);
      const float* ap = (const float*)&av;
      #pragma unroll
      for (int kk = 0; kk < 4; ++kk) {
        const float* bp = (const float*)&bv[kk];
        #pragma unroll
        for (int j = 0; j < 4; ++j) acc[i][j] = fmaf(ap[kk], bp[j], acc[i][j]);
      }
    }
  }
  #pragma unroll
  for (int i = 0; i < 8; ++i) {
    int o = ob + i;
    float s  = acc[i][0]+acc[i][1]+acc[i][2]+acc[i][3];
    float s2 = fmaf(acc[i][0],acc[i][0], fmaf(acc[i][1],acc[i][1], fmaf(acc[i][2],acc[i][2], acc[i][3]*acc[i][3])));
    #pragma unroll
    for (int d = 1; d < 16; d <<= 1) { s += __shfl_xor(s, d); s2 += __shfl_xor(s2, d); }
    if (tn == 0) { atomicAdd(&sum2[b*128+o], s); atomicAdd(&sq2[b*128+o], s2); }
  }
}

// ---------------- k3: layer2 GEMM again -> bn2+relu -> hi/lo split, transposed ----
// thread map swapped (to = t&15) so the transposed stores coalesce.
__global__ __launch_bounds__(256) void k3_split(const float* __restrict__ x,
    const float* __restrict__ w1, const float* __restrict__ b1,
    const float* __restrict__ scale1, const float* __restrict__ shift1,
    const float* __restrict__ w2, const float* __restrict__ b2,
    const float* __restrict__ scale2, const float* __restrict__ shift2,
    u16* __restrict__ h2t_hi, u16* __restrict__ h2t_lo) {
  __shared__ float xs[3][64];
  __shared__ float w1s[64][3];
  __shared__ float b1s[64], sc1s[64], sh1s[64];
  __shared__ float h1s[64][64];
  __shared__ float w2s[128][64];
  int t = threadIdx.x;
  int tile = blockIdx.x;
  int b = tile >> 6;
  int n0 = (tile & 63) << 6;
  if (t < 192) { int c = t >> 6, n = t & 63; xs[c][n] = x[((size_t)b*3 + c)*4096 + n0 + n]; }
  if (t < 64) {
    b1s[t] = b1[t]; sc1s[t] = scale1[t]; sh1s[t] = shift1[t];
    w1s[t][0] = w1[t*3+0]; w1s[t][1] = w1[t*3+1]; w1s[t][2] = w1[t*3+2];
  }
  for (int v = t; v < 2048; v += 256) {
    int row = v >> 4, c4 = (v & 15) << 2;
    int sw = ((row >> 3) & 3) << 2;
    *(float4*)(&w2s[row][c4 ^ sw]) = *(const float4*)(w2 + row*64 + c4);
  }
  __syncthreads();
  for (int idx = t; idx < 4096; idx += 256) {
    int o = idx >> 6, n = idx & 63;
    float pre = fmaf(w1s[o][0], xs[0][n], fmaf(w1s[o][1], xs[1][n], fmaf(w1s[o][2], xs[2][n], b1s[o])));
    h1s[o][n] = fmaxf(fmaf(sc1s[o], pre, sh1s[o]), 0.f);
  }
  __syncthreads();
  int to = t & 15, tn = t >> 4;         // SWAPPED vs k2
  int ob = to << 3, nb = tn << 2;
  int swz = (to & 3) << 2;
  float acc[8][4];
  #pragma unroll
  for (int i = 0; i < 8; ++i) { float bb = b2[ob+i]; acc[i][0]=bb; acc[i][1]=bb; acc[i][2]=bb; acc[i][3]=bb; }
  #pragma unroll 2
  for (int k0 = 0; k0 < 64; k0 += 4) {
    float4 bv[4];
    #pragma unroll
    for (int kk = 0; kk < 4; ++kk) bv[kk] = *(const float4*)(&h1s[k0+kk][nb]);
    #pragma unroll
    for (int i = 0; i < 8; ++i) {
      float4 av = *(const float4*)(&w2s[ob+i][k0 ^ swz]);
      const float* ap = (const float*)&av;
      #pragma unroll
      for (int kk = 0; kk < 4; ++kk) {
        const float* bp = (const float*)&bv[kk];
        #pragma unroll
        for (int j = 0; j < 4; ++j) acc[i][j] = fmaf(ap[kk], bp[j], acc[i][j]);
      }
    }
  }
  // bn2 + relu + hi/lo split; write transposed [b][n][128]
  float sc2v[8], sh2v[8];
  #pragma unroll
  for (int i = 0; i < 8; ++i) { sc2v[i] = scale2[ob+i]; sh2v[i] = shift2[ob+i]; }
  #pragma unroll
  for (int j = 0; j < 4; ++j) {
    int n = n0 + nb + j;
    u32 hiw[4], low[4];
    #pragma unroll
    for (int p = 0; p < 4; ++p) {
      float v0 = fmaxf(fmaf(sc2v[2*p],   acc[2*p][j],   sh2v[2*p]),   0.f);
      float v1 = fmaxf(fmaf(sc2v[2*p+1], acc[2*p+1][j], sh2v[2*p+1]), 0.f);
      u16 h0 = f2bf(v0), h1 = f2bf(v1);
      u16 l0 = f2bf(v0 - bf2f(h0)), l1 = f2bf(v1 - bf2f(h1));
      hiw[p] = (u32)h0 | ((u32)h1 << 16);
      low[p] = (u32)l0 | ((u32)l1 << 16);
    }
    size_t idx = (((size_t)(b << 12) + n) << 7) + ob;
    *(uint4*)(h2t_hi + idx) = make_uint4(hiw[0], hiw[1], hiw[2], hiw[3]);
    *(uint4*)(h2t_lo + idx) = make_uint4(low[0], low[1], low[2], low[3]);
  }
}

// ---------------- k5: bf16x3 MFMA GEMM 128ch -> 1024, fused stats + max/min -------
// grid 256 (1 block/CU), 512 threads (8 waves: 4 o-quarters x 2 n-halves).
// Chunk = 64 points x 128 k, hi+lo planes = 32KB; LDS 64KB double-buffered.
__global__ __launch_bounds__(512, 2) void k5_layer3(
    const u16* __restrict__ h2t_hi, const u16* __restrict__ h2t_lo,
    const float* __restrict__ w3,
    float* __restrict__ sum3, float* __restrict__ sq3,
    float* __restrict__ maxv, float* __restrict__ minv) {
  __shared__ __align__(16) char smem[65536];
  const int t = threadIdx.x;
  const int lane = t & 63;
  const int wid = t >> 6;
  const int wo = wid & 3;             // o quarter (32 o)
  const int wn = wid >> 2;            // n half (32 n)
  const int id = blockIdx.x;
  const int b = ((id & 7) << 2) | ((id >> 3) & 3);   // same-b o-tiles share an XCD
  const int otile = id >> 5;

  const int kb2 = (lane >> 4) << 4;   // byte offset of this lane's 8 k-elems

  // ---- prologue: W3 tile f32 -> bf16 hi (smem[0:32K)) + lo (smem[32K:64K)), swizzled
  {
    const float* wbase = w3 + ((size_t)otile << 14);
    #pragma unroll
    for (int i = 0; i < 2; ++i) {
      int idx = (i << 9) | t;
      int row = idx >> 3;
      int c = (idx & 7) << 4;
      const float* src = wbase + (row << 7) + c;
      float4 f0 = *(const float4*)(src);
      float4 f1 = *(const float4*)(src + 4);
      float4 f2 = *(const float4*)(src + 8);
      float4 f3 = *(const float4*)(src + 12);
      float fv[16] = {f0.x,f0.y,f0.z,f0.w, f1.x,f1.y,f1.z,f1.w,
                      f2.x,f2.y,f2.z,f2.w, f3.x,f3.y,f3.z,f3.w};
      u32 hw[8], lw[8];
      #pragma unroll
      for (int p = 0; p < 8; ++p) {
        u16 h0 = f2bf(fv[2*p]), h1 = f2bf(fv[2*p+1]);
        u16 l0 = f2bf(fv[2*p] - bf2f(h0)), l1 = f2bf(fv[2*p+1] - bf2f(h1));
        hw[p] = (u32)h0 | ((u32)h1 << 16);
        lw[p] = (u32)l0 | ((u32)l1 << 16);
      }
      int byte = (row << 8) | (c << 1);
      int sw = (row & 7) << 4;
      *(uint4*)(smem + (byte ^ sw))              = make_uint4(hw[0],hw[1],hw[2],hw[3]);
      *(uint4*)(smem + ((byte | 16) ^ sw))       = make_uint4(hw[4],hw[5],hw[6],hw[7]);
      *(uint4*)(smem + 32768 + (byte ^ sw))      = make_uint4(lw[0],lw[1],lw[2],lw[3]);
      *(uint4*)(smem + 32768 + ((byte | 16) ^ sw)) = make_uint4(lw[4],lw[5],lw[6],lw[7]);
    }
  }
  __syncthreads();

  // ---- W3 frags -> registers: o = wo*32 + of*16 + (lane&15)
  bf16x8 wf_hi[4][2], wf_lo[4][2];
  #pragma unroll
  for (int of = 0; of < 2; ++of) {
    int row = (wo << 5) | (of << 4) | (lane & 15);
    int sw = (row & 7) << 4;
    #pragma unroll
    for (int ks = 0; ks < 4; ++ks) {
      int a = ((row << 8) | (ks << 6) | kb2) ^ sw;
      wf_hi[ks][of] = *(const bf16x8*)(smem + a);
      wf_lo[ks][of] = *(const bf16x8*)(smem + 32768 + a);
    }
  }
  __syncthreads();   // frag reads done -> buffers reusable

  // ---- staging offsets (chunk-invariant); plane = 16KB per chunk buffer
  const size_t gbase = (size_t)b << 19;
  int ldsu[2], goff[2];
  #pragma unroll
  for (int i = 0; i < 2; ++i) {
    ldsu[i] = (wid << 11) | (i << 10);          // wave-uniform LDS base
    int Lb = ldsu[i] | (lane << 4);
    int gb = Lb ^ (((Lb >> 8) & 7) << 4);       // pre-swizzle the SOURCE
    goff[i] = gb >> 1;                          // u16 elements
  }
  auto STAGE = [&](int c, int p) {
    const u16* gh = h2t_hi + gbase + ((size_t)c << 13);
    const u16* gl = h2t_lo + gbase + ((size_t)c << 13);
    char* lb = smem + (p << 15);
    #pragma unroll
    for (int i = 0; i < 2; ++i) {
      __builtin_amdgcn_global_load_lds(
          (const __attribute__((address_space(1))) u32*)(gh + goff[i]),
          (__attribute__((address_space(3))) u32*)(lb + ldsu[i]), 16, 0, 0);
      __builtin_amdgcn_global_load_lds(
          (const __attribute__((address_space(1))) u32*)(gl + goff[i]),
          (__attribute__((address_space(3))) u32*)(lb + 16384 + ldsu[i]), 16, 0, 0);
    }
  };

  // ---- A-frag addresses: n = wn*32 + nf*16 + (lane&15)
  int a_pre[2], a_sw[2];
  #pragma unroll
  for (int nf = 0; nf < 2; ++nf) {
    int n = (wn << 5) | (nf << 4) | (lane & 15);
    a_pre[nf] = (n << 8) | kb2;
    a_sw[nf] = (n & 7) << 4;
  }

  STAGE(0, 0);
  __syncthreads();   // chunk 0 landed (barrier drains vmcnt)

  f32x4 acc[2][2];
  float rs[2] = {0.f,0.f};
  float rq[2] = {0.f,0.f};
  float rmx[2] = {-3.4e38f,-3.4e38f};
  float rmn[2] = { 3.4e38f, 3.4e38f};
  const f32x4 zero4 = {0.f,0.f,0.f,0.f};

  for (int c = 0; c < 64; ++c) {
    int p = c & 1;
    if (c < 63) STAGE(c + 1, p ^ 1);
    const char* bufb = smem + (p << 15);
    #pragma unroll
    for (int ks = 0; ks < 4; ++ks) {
      int a0 = (a_pre[0] | (ks << 6)) ^ a_sw[0];
      int a1 = (a_pre[1] | (ks << 6)) ^ a_sw[1];
      bf16x8 a0h = *(const bf16x8*)(bufb + a0);
      bf16x8 a1h = *(const bf16x8*)(bufb + a1);
      bf16x8 a0l = *(const bf16x8*)(bufb + 16384 + a0);
      bf16x8 a1l = *(const bf16x8*)(bufb + 16384 + a1);
      #pragma unroll
      for (int of = 0; of < 2; ++of) {
        f32x4 c0 = (ks == 0) ? zero4 : acc[0][of];
        f32x4 c1 = (ks == 0) ? zero4 : acc[1][of];
        c0 = __builtin_amdgcn_mfma_f32_16x16x32_bf16(a0l, wf_hi[ks][of], c0, 0, 0, 0);
        c1 = __builtin_amdgcn_mfma_f32_16x16x32_bf16(a1l, wf_hi[ks][of], c1, 0, 0, 0);
        c0 = __builtin_amdgcn_mfma_f32_16x16x32_bf16(a0h, wf_lo[ks][of], c0, 0, 0, 0);
        c1 = __builtin_amdgcn_mfma_f32_16x16x32_bf16(a1h, wf_lo[ks][of], c1, 0, 0, 0);
        acc[0][of] = __builtin_amdgcn_mfma_f32_16x16x32_bf16(a0h, wf_hi[ks][of], c0, 0, 0, 0);
        acc[1][of] = __builtin_amdgcn_mfma_f32_16x16x32_bf16(a1h, wf_hi[ks][of], c1, 0, 0, 0);
      }
    }
    // fused stats on this chunk's outputs (pre-bias h3, ~f32-exact)
    #pragma unroll
    for (int of = 0; of < 2; ++of) {
      #pragma unroll
      for (int nf = 0; nf < 2; ++nf) {
        f32x4 v = acc[nf][of];
        rs[of] += (v[0] + v[1]) + (v[2] + v[3]);
        rq[of] = fmaf(v[0],v[0], fmaf(v[1],v[1], fmaf(v[2],v[2], fmaf(v[3],v[3], rq[of]))));
        rmx[of] = fmaxf(rmx[of], fmaxf(fmaxf(v[0],v[1]), fmaxf(v[2],v[3])));
        rmn[of] = fminf(rmn[of], fminf(fminf(v[0],v[1]), fminf(v[2],v[3])));
      }
    }
    __syncthreads();   // staged chunk landed; buffer p free for next stage
  }

  // ---- cross-lane (o = lane&15 preserved), then cross-wave via LDS
  #pragma unroll
  for (int of = 0; of < 2; ++of) {
    rs[of] += __shfl_xor(rs[of], 16); rs[of] += __shfl_xor(rs[of], 32);
    rq[of] += __shfl_xor(rq[of], 16); rq[of] += __shfl_xor(rq[of], 32);
    rmx[of] = fmaxf(rmx[of], __shfl_xor(rmx[of], 16)); rmx[of] = fmaxf(rmx[of], __shfl_xor(rmx[of], 32));
    rmn[of] = fminf(rmn[of], __shfl_xor(rmn[of], 16)); rmn[of] = fminf(rmn[of], __shfl_xor(rmn[of], 32));
  }
  float* part = (float*)smem;   // [2 wn][128 o][4]
  if (lane < 16) {
    #pragma unroll
    for (int of = 0; of < 2; ++of) {
      int ol = (wo << 5) | (of << 4) | lane;
      float* pp = part + (((wn << 7) | ol) << 2);
      pp[0] = rs[of]; pp[1] = rq[of]; pp[2] = rmx[of]; pp[3] = rmn[of];
    }
  }
  __syncthreads();
  if (t < 128) {
    float S = 0.f, Q = 0.f, MX = -3.4e38f, MN = 3.4e38f;
    #pragma unroll
    for (int wq = 0; wq < 2; ++wq) {
      const float* pp = part + (((wq << 7) | t) << 2);
      S += pp[0]; Q += pp[1]; MX = fmaxf(MX, pp[2]); MN = fminf(MN, pp[3]);
    }
    int go = (b << 10) | (otile << 7) | t;
    sum3[go] = S; sq3[go] = Q; maxv[go] = MX; minv[go] = MN;
  }
}

// ---------------- finalize stats3 (+bias fold) + pooled ---------------------------
__global__ void k_fin3_pool(const float* __restrict__ sum3, const float* __restrict__ sq3,
    const float* __restrict__ maxv, const float* __restrict__ minv,
    const float* __restrict__ b3,
    const float* __restrict__ g, const float* __restrict__ be, float* __restrict__ pool) {
  int o = blockIdx.x*256 + threadIdx.x;
  float S = 0.f, Q = 0.f;
  for (int b = 0; b < 32; ++b) { S += sum3[b*1024+o]; Q += sq3[b*1024+o]; }
  const float inv = 1.f/131072.f;
  float ma = S*inv;
  float m = ma + b3[o];              // bias folded into mean; variance shift-invariant
  float var = Q*inv - ma*ma;
  float sc = g[o]*rsqrtf(var + EPS);
  float sh = be[o] - sc*m;
  bool pos = (sc >= 0.f);
  for (int b = 0; b < 32; ++b) {
    float v = (pos ? maxv[b*1024+o] : minv[b*1024+o]) + b3[o];
    pool[b*1024+o] = fmaxf(fmaf(sc, v, sh), 0.f);
  }
}

// ---------------- fused FC + batch-BN + ReLU --------------------------------------
__global__ __launch_bounds__(256) void k_fc_bn_relu(const float* __restrict__ in,
    const float* __restrict__ w, const float* __restrict__ fb,
    const float* __restrict__ g, const float* __restrict__ be,
    float* __restrict__ out, int K, int F) {
  __shared__ float wrow[1024];
  __shared__ float preb[32];
  int o = blockIdx.x, t = threadIdx.x;
  for (int k = t; k < K; k += 256) wrow[k] = w[(size_t)o*K + k];
  __syncthreads();
  int b = t >> 3, j = t & 7;
  int per = K >> 3;
  const float* inb = in + (size_t)b*K + j*per;
  const float* wp  = wrow + j*per;
  float p = 0.f;
  for (int k = 0; k < per; ++k) p = fmaf(inb[k], wp[k], p);
  p += __shfl_xor(p, 1); p += __shfl_xor(p, 2); p += __shfl_xor(p, 4);
  if (j == 0) preb[b] = p + fb[o];
  __syncthreads();
  if (t < 32) {
    float v = preb[t];
    float s = v;
    #pragma unroll
    for (int d = 1; d < 32; d <<= 1) s += __shfl_xor(s, d);
    float m = s * 0.03125f;
    float dv = v - m;
    float q = dv*dv;
    #pragma unroll
    for (int d = 1; d < 32; d <<= 1) q += __shfl_xor(q, d);
    float var = q * 0.03125f;
    float sc = g[o]*rsqrtf(var + EPS);
    out[(size_t)t*F + o] = fmaxf(fmaf(sc, dv, be[o]), 0.f);
  }
}

// ---------------- angles + Euler->rotation ----------------------------------------
__global__ __launch_bounds__(128) void k_final(const float* __restrict__ h6,
    const float* __restrict__ fw4, const float* __restrict__ fb4, float* __restrict__ out) {
  __shared__ float angs[32][3];
  int t = threadIdx.x;
  if (t < 96) {
    int b = t / 3, j = t % 3;
    float p = 0.f;
    #pragma unroll 4
    for (int k = 0; k < 128; ++k) p = fmaf(h6[b*128+k], fw4[j*128+k], p);
    angs[b][j] = (p + fb4[j]) * PI_F;
  }
  __syncthreads();
  if (t < 32) {
    float a = angs[t][0], bb = angs[t][1], c = angs[t][2];
    float sa, ca; sincosf(a,  &sa, &ca);
    float sb, cb; sincosf(bb, &sb, &cb);
    float sc, cc; sincosf(c,  &sc, &cc);
    float* o9 = out + t*9;
    o9[0] = cc*cb;
    o9[1] = fmaf(cc*sb, sa, -sc*ca);
    o9[2] = fmaf(cc*sb, ca,  sc*sa);
    o9[3] = sc*cb;
    o9[4] = fmaf(sc*sb, sa,  cc*ca);
    o9[5] = fmaf(sc*sb, ca, -cc*sa);
    o9[6] = -sb;
    o9[7] = cb*sa;
    o9[8] = cb*ca;
  }
}

extern "C" void kernel_launch(void* const* d_in, const int* in_sizes, int n_in,
                              void* d_out, int out_size, void* d_ws, size_t ws_size,
                              hipStream_t stream) {
  (void)in_sizes; (void)n_in; (void)out_size; (void)ws_size;
  const float* x   = (const float*)d_in[0];
  const float* w1  = (const float*)d_in[1];
  const float* b1  = (const float*)d_in[2];
  const float* g1  = (const float*)d_in[3];
  const float* be1 = (const float*)d_in[4];
  const float* w2  = (const float*)d_in[5];
  const float* b2  = (const float*)d_in[6];
  const float* g2  = (const float*)d_in[7];
  const float* be2 = (const float*)d_in[8];
  const float* w3  = (const float*)d_in[9];
  const float* b3  = (const float*)d_in[10];
  const float* g3  = (const float*)d_in[11];
  const float* be3 = (const float*)d_in[12];
  const float* fw1 = (const float*)d_in[13];
  const float* fb1 = (const float*)d_in[14];
  const float* g4  = (const float*)d_in[15];
  const float* be4 = (const float*)d_in[16];
  const float* fw2 = (const float*)d_in[17];
  const float* fb2 = (const float*)d_in[18];
  const float* g5p = (const float*)d_in[19];
  const float* be5 = (const float*)d_in[20];
  const float* fw3 = (const float*)d_in[21];
  const float* fb3 = (const float*)d_in[22];
  const float* g6  = (const float*)d_in[23];
  const float* be6 = (const float*)d_in[24];
  const float* fw4 = (const float*)d_in[25];
  const float* fb4 = (const float*)d_in[26];

  u16* h2t_hi = (u16*)d_ws;                     // 32 MiB
  u16* h2t_lo = (u16*)d_ws + 16777216;          // 32 MiB
  float* acc0 = (float*)d_ws + 16777216;        // after the two bf16 planes
  float* sum1 = acc0 +      0;                  // 64
  float* sq1  = acc0 +     64;                  // 64
  float* sum2 = acc0 +    128;                  // 4096
  float* sq2  = acc0 +   4224;                  // 4096
  float* scale1 = acc0 + 8320;
  float* shift1 = acc0 + 8384;
  float* scale2 = acc0 + 8448;
  float* shift2 = acc0 + 8576;
  float* sum3 = acc0 +   8704;                  // 32768
  float* sq3  = acc0 +  41472;                  // 32768
  float* maxv = acc0 +  74240;                  // 32768
  float* minv = acc0 + 107008;                  // 32768
  float* pool = acc0 + 139776;                  // 32768
  float* h4v  = acc0 + 172544;                  // 16384
  float* h5v  = acc0 + 188928;                  // 8192
  float* h6v  = acc0 + 197120;                  // 4096

  hipMemsetAsync(acc0, 0, 8320ull*4, stream);   // atomic accumulators (layers 1,2)

  k1_stats1<<<512, 64, 0, stream>>>(x, w1, b1, sum1, sq1);
  k_finstats<<<1, 64, 0, stream>>>(sum1, sq1, g1, be1, scale1, shift1, 64, 1);
  k2_stats2<<<2048, 256, 0, stream>>>(x, w1, b1, scale1, shift1, w2, b2, sum2, sq2);
  k_finstats<<<1, 128, 0, stream>>>(sum2, sq2, g2, be2, scale2, shift2, 128, 32);
  k3_split<<<2048, 256, 0, stream>>>(x, w1, b1, scale1, shift1, w2, b2, scale2, shift2, h2t_hi, h2t_lo);
  k5_layer3<<<256, 512, 0, stream>>>(h2t_hi, h2t_lo, w3, sum3, sq3, maxv, minv);
  k_fin3_pool<<<4, 256, 0, stream>>>(sum3, sq3, maxv, minv, b3, g3, be3, pool);
  k_fc_bn_relu<<<512, 256, 0, stream>>>(pool, fw1, fb1, g4, be4, h4v, 1024, 512);
  k_fc_bn_relu<<<256, 256, 0, stream>>>(h4v, fw2, fb2, g5p, be5, h5v, 512, 256);
  k_fc_bn_relu<<<128, 256, 0, stream>>>(h5v, fw3, fb3, g6, be6, h6v, 256, 128);
  k_final<<<1, 128, 0, stream>>>(h6v, fw4, fb4, (float*)d_out);
}